// Round 1
// baseline (215.665 us; speedup 1.0000x reference)
//
#include <hip/hip_runtime.h>

#define N_ATOMS 2048
#define NSPEC 7
#define NR 16
#define NFEAT 112          // 7 species * 16 radial shifts; aev[112:1008] is zero padding
#define RCR_F 5.2f
#define H0 256
#define H1 192
#define H2 160
#define W0_PITCH 1008      // W0 rows are 1008 wide; only first 112 columns matter

// ---- workspace layout (byte offsets into d_ws; poisoned 0xAA each call, we init all) ----
#define WS_SEG     0         // int[8]   species segment starts (seg[7] = N)
#define WS_SCOORD  16384     // float4[2048] species-sorted coordinates
#define WS_AEV     65536     // float[2048*112] AEV per sorted atom
#define WS_H0BUF   1048576   // float[2048*256]
#define WS_H1BUF   3145728   // float[2048*192]

__device__ __forceinline__ float celu01(float x) {
    // celu(x, alpha=0.1) = max(x,0) + min(0, 0.1*expm1(x/0.1))
    return x > 0.f ? x : 0.1f * (__expf(x * 10.f) - 1.f);
}

__device__ __forceinline__ int spec_of(const int* __restrict__ seg, int p) {
    int s = 0;
#pragma unroll
    for (int i = 1; i < NSPEC; i++) s += (p >= seg[i]) ? 1 : 0;
    return s;
}

// ---------------- K0: counting sort by species + init ----------------
__global__ __launch_bounds__(256) void sort_kernel(const int* __restrict__ species,
                                                   const float* __restrict__ coords,
                                                   int* __restrict__ seg,
                                                   float4* __restrict__ scoord,
                                                   float* __restrict__ out) {
    __shared__ int cnt[NSPEC];
    __shared__ int cur[NSPEC];
    int t = threadIdx.x;
    if (t < NSPEC) cnt[t] = 0;
    __syncthreads();
    for (int a = t; a < N_ATOMS; a += 256) atomicAdd(&cnt[species[a]], 1);
    __syncthreads();
    if (t == 0) {
        int run = 0;
        for (int s = 0; s < NSPEC; s++) { seg[s] = run; cur[s] = run; run += cnt[s]; }
        seg[NSPEC] = run;
        out[0] = 0.0f;   // d_out is poisoned before every call
    }
    __syncthreads();
    for (int a = t; a < N_ATOMS; a += 256) {
        int sp = species[a];
        int pos = atomicAdd(&cur[sp], 1);
        scoord[pos] = make_float4(coords[3*a], coords[3*a+1], coords[3*a+2], 0.f);
    }
}

// ---------------- K1: radial AEV, one wave per (sorted) atom ----------------
// lane = s*8 + c : species s in [0,7) (s==7 idle), chunk c of 8 walking segment s interleaved.
__global__ __launch_bounds__(64) void aev_kernel(const float4* __restrict__ scoord,
                                                 const int* __restrict__ seg,
                                                 const float* __restrict__ ShfR,
                                                 const float* __restrict__ EtaR,
                                                 float* __restrict__ aev) {
    int p = blockIdx.x;
    int lane = threadIdx.x;
    int s = lane >> 3, c = lane & 7;
    float4 ci = scoord[p];
    float eta = EtaR[0];
    float shf[NR];
#pragma unroll
    for (int r = 0; r < NR; r++) shf[r] = ShfR[r];   // uniform -> SGPRs
    float acc[NR];
#pragma unroll
    for (int r = 0; r < NR; r++) acc[r] = 0.f;

    int kbeg = 0, kend = 0;
    if (s < NSPEC) { kbeg = seg[s] + c; kend = seg[s + 1]; }
    const float rc2 = RCR_F * RCR_F;
    const float cosk = 3.14159265358979f / RCR_F;

    for (int k = kbeg; k < kend; k += 8) {
        float4 cj = scoord[k];
        float dx = ci.x - cj.x, dy = ci.y - cj.y, dz = ci.z - cj.z;
        float dsq = dx*dx + dy*dy + dz*dz;
        bool valid = (dsq > 0.f) && (dsq <= rc2);   // excludes self (j==i)
        float d = sqrtf(dsq);
        float fc = 0.5f * __cosf(d * cosk) + 0.5f;
        fc = valid ? fc : 0.f;
#pragma unroll
        for (int r = 0; r < NR; r++) {
            float u = d - shf[r];
            acc[r] = fmaf(__expf(-eta * u * u), fc, acc[r]);  // underflows gracefully to 0
        }
    }
    // reduce over the 8 chunk-lanes of each species group (xor masks stay inside group)
#pragma unroll
    for (int r = 0; r < NR; r++) {
        float v = acc[r];
        v += __shfl_xor(v, 1);
        v += __shfl_xor(v, 2);
        v += __shfl_xor(v, 4);
        acc[r] = v;
    }
    if (s < NSPEC && c == 0) {
        float* dst = aev + p * NFEAT + s * NR;
#pragma unroll
        for (int r = 0; r < NR; r += 4)
            *(float4*)(dst + r) = make_float4(acc[r], acc[r+1], acc[r+2], acc[r+3]);
    }
}

// ---------------- K2a: layer0  aev[112] -> h0[256]  (block = 8 sorted atoms) ----------------
__global__ __launch_bounds__(256) void mlp0_kernel(const float* __restrict__ W0,
                                                   const float* __restrict__ b0,
                                                   const float* __restrict__ aev,
                                                   const int* __restrict__ seg,
                                                   float* __restrict__ h0out) {
    int p0 = blockIdx.x * 8;
    int o = threadIdx.x;
    int sp[8];
#pragma unroll
    for (int m = 0; m < 8; m++) sp[m] = spec_of(seg, p0 + m);

    int m = 0;
    while (m < 8) {
        int s = sp[m]; int mE = m + 1;
        while (mE < 8 && sp[mE] == s) mE++;
        const float* Wrow = W0 + (size_t)(s * H0 + o) * W0_PITCH;
        float bias = b0[s * H0 + o];
        if (m == 0 && mE == 8) {             // fast path: whole chunk same species
            float acc[8];
#pragma unroll
            for (int q = 0; q < 8; q++) acc[q] = 0.f;
            for (int h = 0; h < NFEAT; h += 4) {
                float4 w = *(const float4*)(Wrow + h);
#pragma unroll
                for (int q = 0; q < 8; q++) {
                    float4 a = *(const float4*)(aev + (p0 + q) * NFEAT + h); // uniform -> s_load
                    acc[q] += w.x*a.x + w.y*a.y + w.z*a.z + w.w*a.w;
                }
            }
#pragma unroll
            for (int q = 0; q < 8; q++)
                h0out[(p0 + q) * H0 + o] = celu01(acc[q] + bias);
        } else {                             // boundary chunk (rare): per-atom
            for (int q = m; q < mE; q++) {
                float acc = 0.f;
                for (int h = 0; h < NFEAT; h += 4) {
                    float4 w = *(const float4*)(Wrow + h);
                    float4 a = *(const float4*)(aev + (p0 + q) * NFEAT + h);
                    acc += w.x*a.x + w.y*a.y + w.z*a.z + w.w*a.w;
                }
                h0out[(p0 + q) * H0 + o] = celu01(acc + bias);
            }
        }
        m = mE;
    }
}

// ---------------- K2b: layer1  h0[256] -> h1[192] ----------------
__global__ __launch_bounds__(192) void mlp1_kernel(const float* __restrict__ W1,
                                                   const float* __restrict__ b1,
                                                   const float* __restrict__ h0,
                                                   const int* __restrict__ seg,
                                                   float* __restrict__ h1out) {
    int p0 = blockIdx.x * 8;
    int o = threadIdx.x;   // < 192, all active
    int sp[8];
#pragma unroll
    for (int m = 0; m < 8; m++) sp[m] = spec_of(seg, p0 + m);

    int m = 0;
    while (m < 8) {
        int s = sp[m]; int mE = m + 1;
        while (mE < 8 && sp[mE] == s) mE++;
        const float* Wrow = W1 + (size_t)(s * H1 + o) * H0;
        float bias = b1[s * H1 + o];
        if (m == 0 && mE == 8) {
            float acc[8];
#pragma unroll
            for (int q = 0; q < 8; q++) acc[q] = 0.f;
            for (int h = 0; h < H0; h += 4) {
                float4 w = *(const float4*)(Wrow + h);
#pragma unroll
                for (int q = 0; q < 8; q++) {
                    float4 a = *(const float4*)(h0 + (p0 + q) * H0 + h);
                    acc[q] += w.x*a.x + w.y*a.y + w.z*a.z + w.w*a.w;
                }
            }
#pragma unroll
            for (int q = 0; q < 8; q++)
                h1out[(p0 + q) * H1 + o] = celu01(acc[q] + bias);
        } else {
            for (int q = m; q < mE; q++) {
                float acc = 0.f;
                for (int h = 0; h < H0; h += 4) {
                    float4 w = *(const float4*)(Wrow + h);
                    float4 a = *(const float4*)(h0 + (p0 + q) * H0 + h);
                    acc += w.x*a.x + w.y*a.y + w.z*a.z + w.w*a.w;
                }
                h1out[(p0 + q) * H1 + o] = celu01(acc + bias);
            }
        }
        m = mE;
    }
}

// ---------------- K2c: layer2 + final dot + global sum ----------------
__global__ __launch_bounds__(192) void mlp2_kernel(const float* __restrict__ W2,
                                                   const float* __restrict__ b2,
                                                   const float* __restrict__ Wf,
                                                   const float* __restrict__ bf,
                                                   const float* __restrict__ h1,
                                                   const int* __restrict__ seg,
                                                   float* __restrict__ out) {
    __shared__ float bsum;
    int p0 = blockIdx.x * 8;
    int o = threadIdx.x;   // < 192; only o<160 compute
    if (o == 0) bsum = 0.f;
    __syncthreads();
    int sp[8];
#pragma unroll
    for (int m = 0; m < 8; m++) sp[m] = spec_of(seg, p0 + m);

    float contrib = 0.f;
    int m = 0;
    while (m < 8) {
        int s = sp[m]; int mE = m + 1;
        while (mE < 8 && sp[mE] == s) mE++;
        if (o < H2) {
            const float* Wrow = W2 + (size_t)(s * H2 + o) * H1;
            float bias = b2[s * H2 + o];
            float wf = Wf[s * H2 + o];
            if (m == 0 && mE == 8) {
                float acc[8];
#pragma unroll
                for (int q = 0; q < 8; q++) acc[q] = 0.f;
                for (int h = 0; h < H1; h += 4) {
                    float4 w = *(const float4*)(Wrow + h);
#pragma unroll
                    for (int q = 0; q < 8; q++) {
                        float4 a = *(const float4*)(h1 + (p0 + q) * H1 + h);
                        acc[q] += w.x*a.x + w.y*a.y + w.z*a.z + w.w*a.w;
                    }
                }
#pragma unroll
                for (int q = 0; q < 8; q++)
                    contrib += wf * celu01(acc[q] + bias);
            } else {
                for (int q = m; q < mE; q++) {
                    float acc = 0.f;
                    for (int h = 0; h < H1; h += 4) {
                        float4 w = *(const float4*)(Wrow + h);
                        float4 a = *(const float4*)(h1 + (p0 + q) * H1 + h);
                        acc += w.x*a.x + w.y*a.y + w.z*a.z + w.w*a.w;
                    }
                    contrib += wf * celu01(acc + bias);
                }
            }
        }
        if (o == 0) contrib += (float)(mE - m) * bf[s];  // bias of final layer, once per atom
        m = mE;
    }
    // block reduction: 3 waves of 64
    float v = contrib;
    v += __shfl_down(v, 32);
    v += __shfl_down(v, 16);
    v += __shfl_down(v, 8);
    v += __shfl_down(v, 4);
    v += __shfl_down(v, 2);
    v += __shfl_down(v, 1);
    if ((o & 63) == 0) atomicAdd(&bsum, v);
    __syncthreads();
    if (o == 0) atomicAdd(out, bsum);
}

extern "C" void kernel_launch(void* const* d_in, const int* in_sizes, int n_in,
                              void* d_out, int out_size, void* d_ws, size_t ws_size,
                              hipStream_t stream) {
    const int*   species = (const int*)d_in[0];
    const float* coords  = (const float*)d_in[1];
    const float* EtaR    = (const float*)d_in[2];
    const float* ShfR    = (const float*)d_in[3];
    const float* W0      = (const float*)d_in[4];
    const float* b0      = (const float*)d_in[5];
    const float* W1      = (const float*)d_in[6];
    const float* b1      = (const float*)d_in[7];
    const float* W2      = (const float*)d_in[8];
    const float* b2      = (const float*)d_in[9];
    const float* Wf      = (const float*)d_in[10];
    const float* bf      = (const float*)d_in[11];
    float* out = (float*)d_out;
    char* ws = (char*)d_ws;

    int*    seg    = (int*)(ws + WS_SEG);
    float4* scoord = (float4*)(ws + WS_SCOORD);
    float*  aev    = (float*)(ws + WS_AEV);
    float*  h0buf  = (float*)(ws + WS_H0BUF);
    float*  h1buf  = (float*)(ws + WS_H1BUF);

    hipLaunchKernelGGL(sort_kernel, dim3(1), dim3(256), 0, stream,
                       species, coords, seg, scoord, out);
    hipLaunchKernelGGL(aev_kernel, dim3(N_ATOMS), dim3(64), 0, stream,
                       scoord, seg, ShfR, EtaR, aev);
    hipLaunchKernelGGL(mlp0_kernel, dim3(N_ATOMS / 8), dim3(256), 0, stream,
                       W0, b0, aev, seg, h0buf);
    hipLaunchKernelGGL(mlp1_kernel, dim3(N_ATOMS / 8), dim3(192), 0, stream,
                       W1, b1, h0buf, seg, h1buf);
    hipLaunchKernelGGL(mlp2_kernel, dim3(N_ATOMS / 8), dim3(192), 0, stream,
                       W2, b2, Wf, bf, h1buf, seg, out);
}

// Round 2
// 205.597 us; speedup vs baseline: 1.0490x; 1.0490x over previous
//
#include <hip/hip_runtime.h>

#define N_ATOMS 2048
#define NSPEC 7
#define NR 16
#define NFEAT 112          // 7 species * 16 radial shifts; aev[112:1008] is zero padding
#define RCR_F 5.2f
#define H0 256
#define H1 192
#define H2 160
#define W0_PITCH 1008      // W0 rows are 1008 wide; only first 112 columns matter

// ---- workspace layout (byte offsets into d_ws; poisoned 0xAA each call, we init all) ----
#define WS_SEG     0         // int[8]   species segment starts (seg[7] = N)
#define WS_SCOORD  16384     // float4[2048] species-sorted coordinates
#define WS_AEV     65536     // float[2048*112] AEV per sorted atom
#define WS_H0BUF   1048576   // float[2048*256]
#define WS_H1BUF   3145728   // float[2048*192]

__device__ __forceinline__ float celu01(float x) {
    return x > 0.f ? x : 0.1f * (__expf(x * 10.f) - 1.f);
}

__device__ __forceinline__ int spec_of(const int* __restrict__ seg, int p) {
    int s = 0;
#pragma unroll
    for (int i = 1; i < NSPEC; i++) s += (p >= seg[i]) ? 1 : 0;
    return s;
}

// ---------------- K0: counting sort by species + init ----------------
__global__ __launch_bounds__(256) void sort_kernel(const int* __restrict__ species,
                                                   const float* __restrict__ coords,
                                                   int* __restrict__ seg,
                                                   float4* __restrict__ scoord,
                                                   float* __restrict__ out) {
    __shared__ int cnt[NSPEC];
    __shared__ int cur[NSPEC];
    int t = threadIdx.x;
    if (t < NSPEC) cnt[t] = 0;
    __syncthreads();
    for (int a = t; a < N_ATOMS; a += 256) atomicAdd(&cnt[species[a]], 1);
    __syncthreads();
    if (t == 0) {
        int run = 0;
        for (int s = 0; s < NSPEC; s++) { seg[s] = run; cur[s] = run; run += cnt[s]; }
        seg[NSPEC] = run;
        out[0] = 0.0f;   // d_out is poisoned before every call
    }
    __syncthreads();
    for (int a = t; a < N_ATOMS; a += 256) {
        int sp = species[a];
        int pos = atomicAdd(&cur[sp], 1);
        scoord[pos] = make_float4(coords[3*a], coords[3*a+1], coords[3*a+2], 0.f);
    }
}

// ---------------- K1: radial AEV, one 128-thread block (2 waves) per sorted atom ----
// lane L = s*16 + c : species s in [0,7), chunk c of 16 walking segment s interleaved.
// Wave0 holds s=0..3, wave1 holds s=4..6 (+16 idle lanes); 16-lane shfl groups stay in-wave.
__global__ __launch_bounds__(128) void aev_kernel(const float4* __restrict__ scoord,
                                                  const int* __restrict__ seg,
                                                  const float* __restrict__ ShfR,
                                                  const float* __restrict__ EtaR,
                                                  float* __restrict__ aev) {
    int p = blockIdx.x;
    int L = threadIdx.x;
    int s = L >> 4, c = L & 15;
    float4 ci = scoord[p];
    float eta = EtaR[0];
    float shf[NR];
#pragma unroll
    for (int r = 0; r < NR; r++) shf[r] = ShfR[r];   // uniform -> SGPRs
    float acc[NR];
#pragma unroll
    for (int r = 0; r < NR; r++) acc[r] = 0.f;

    int kbeg = 0, kend = 0;
    if (s < NSPEC) { kbeg = seg[s] + c; kend = seg[s + 1]; }
    const float rc2 = RCR_F * RCR_F;
    const float cosk = 3.14159265358979f / RCR_F;

    for (int k = kbeg; k < kend; k += 16) {
        float4 cj = scoord[k];
        float dx = ci.x - cj.x, dy = ci.y - cj.y, dz = ci.z - cj.z;
        float dsq = dx*dx + dy*dy + dz*dz;
        bool valid = (dsq > 0.f) && (dsq <= rc2);   // excludes self (j==i)
        float d = sqrtf(dsq);
        float fc = 0.5f * __cosf(d * cosk) + 0.5f;
        fc = valid ? fc : 0.f;
#pragma unroll
        for (int r = 0; r < NR; r++) {
            float u = d - shf[r];
            acc[r] = fmaf(__expf(-eta * u * u), fc, acc[r]);  // underflow -> 0, matches ref
        }
    }
    // reduce over the 16 chunk-lanes of each species group (xor masks stay inside group)
#pragma unroll
    for (int r = 0; r < NR; r++) {
        float v = acc[r];
        v += __shfl_xor(v, 1);
        v += __shfl_xor(v, 2);
        v += __shfl_xor(v, 4);
        v += __shfl_xor(v, 8);
        acc[r] = v;
    }
    if (s < NSPEC && c == 0) {
        float* dst = aev + p * NFEAT + s * NR;
#pragma unroll
        for (int r = 0; r < NR; r += 4)
            *(float4*)(dst + r) = make_float4(acc[r], acc[r+1], acc[r+2], acc[r+3]);
    }
}

// ================= MLP layers: block = 8 sorted atoms =================
// Thread t = o*4 + ks: output row o, k-slice ks of 4. The 4 slices of one
// output read 16 consecutive floats per iteration (coalesced 64B), partial
// sums reduce with shfl_xor(1),(2) inside the wave. 4x the waves of the
// thread-per-output version at identical weight traffic.

// ---------------- K2a: layer0  aev[112] -> h0[256], block 1024 ----------------
__global__ __launch_bounds__(1024) void mlp0_kernel(const float* __restrict__ W0,
                                                    const float* __restrict__ b0,
                                                    const float* __restrict__ aev,
                                                    const int* __restrict__ seg,
                                                    float* __restrict__ h0out) {
    int p0 = blockIdx.x * 8;
    int t = threadIdx.x;
    int o = t >> 2, ks = t & 3;
    int sp[8];
#pragma unroll
    for (int m = 0; m < 8; m++) sp[m] = spec_of(seg, p0 + m);

    int m = 0;
    while (m < 8) {
        int s = sp[m]; int mE = m + 1;
        while (mE < 8 && sp[mE] == s) mE++;
        const float* Wrow = W0 + (size_t)(s * H0 + o) * W0_PITCH + ks * 4;
        float bias = b0[s * H0 + o];
        float acc[8];
#pragma unroll
        for (int q = 0; q < 8; q++) acc[q] = 0.f;
        for (int i = 0; i < NFEAT / 16; i++) {
            int h = i * 16;
            float4 w = *(const float4*)(Wrow + h);
            for (int q = m; q < mE; q++) {
                float4 a = *(const float4*)(aev + (p0 + q) * NFEAT + h + ks * 4);
                acc[q] += w.x*a.x + w.y*a.y + w.z*a.z + w.w*a.w;
            }
        }
        for (int q = m; q < mE; q++) {
            float v = acc[q];
            v += __shfl_xor(v, 1);
            v += __shfl_xor(v, 2);
            if (ks == 0) h0out[(p0 + q) * H0 + o] = celu01(v + bias);
        }
        m = mE;
    }
}

// ---------------- K2b: layer1  h0[256] -> h1[192], block 768 ----------------
__global__ __launch_bounds__(768) void mlp1_kernel(const float* __restrict__ W1,
                                                   const float* __restrict__ b1,
                                                   const float* __restrict__ h0,
                                                   const int* __restrict__ seg,
                                                   float* __restrict__ h1out) {
    int p0 = blockIdx.x * 8;
    int t = threadIdx.x;
    int o = t >> 2, ks = t & 3;
    int sp[8];
#pragma unroll
    for (int m = 0; m < 8; m++) sp[m] = spec_of(seg, p0 + m);

    int m = 0;
    while (m < 8) {
        int s = sp[m]; int mE = m + 1;
        while (mE < 8 && sp[mE] == s) mE++;
        const float* Wrow = W1 + (size_t)(s * H1 + o) * H0 + ks * 4;
        float bias = b1[s * H1 + o];
        float acc[8];
#pragma unroll
        for (int q = 0; q < 8; q++) acc[q] = 0.f;
        for (int i = 0; i < H0 / 16; i++) {
            int h = i * 16;
            float4 w = *(const float4*)(Wrow + h);
            for (int q = m; q < mE; q++) {
                float4 a = *(const float4*)(h0 + (p0 + q) * H0 + h + ks * 4);
                acc[q] += w.x*a.x + w.y*a.y + w.z*a.z + w.w*a.w;
            }
        }
        for (int q = m; q < mE; q++) {
            float v = acc[q];
            v += __shfl_xor(v, 1);
            v += __shfl_xor(v, 2);
            if (ks == 0) h1out[(p0 + q) * H1 + o] = celu01(v + bias);
        }
        m = mE;
    }
}

// ---------------- K2c: layer2 + final dot + global sum, block 640 ----------------
__global__ __launch_bounds__(640) void mlp2_kernel(const float* __restrict__ W2,
                                                   const float* __restrict__ b2,
                                                   const float* __restrict__ Wf,
                                                   const float* __restrict__ bf,
                                                   const float* __restrict__ h1,
                                                   const int* __restrict__ seg,
                                                   float* __restrict__ out) {
    __shared__ float bsum;
    int p0 = blockIdx.x * 8;
    int t = threadIdx.x;           // < 640 = 160*4
    int o = t >> 2, ks = t & 3;
    if (t == 0) bsum = 0.f;
    __syncthreads();
    int sp[8];
#pragma unroll
    for (int m = 0; m < 8; m++) sp[m] = spec_of(seg, p0 + m);

    float contrib = 0.f;
    int m = 0;
    while (m < 8) {
        int s = sp[m]; int mE = m + 1;
        while (mE < 8 && sp[mE] == s) mE++;
        const float* Wrow = W2 + (size_t)(s * H2 + o) * H1 + ks * 4;
        float bias = b2[s * H2 + o];
        float wf = Wf[s * H2 + o];
        float acc[8];
#pragma unroll
        for (int q = 0; q < 8; q++) acc[q] = 0.f;
        for (int i = 0; i < H1 / 16; i++) {
            int h = i * 16;
            float4 w = *(const float4*)(Wrow + h);
            for (int q = m; q < mE; q++) {
                float4 a = *(const float4*)(h1 + (p0 + q) * H1 + h + ks * 4);
                acc[q] += w.x*a.x + w.y*a.y + w.z*a.z + w.w*a.w;
            }
        }
        for (int q = m; q < mE; q++) {
            float v = acc[q];
            v += __shfl_xor(v, 1);
            v += __shfl_xor(v, 2);
            if (ks == 0) contrib += wf * celu01(v + bias);
        }
        if (t == 0) contrib += (float)(mE - m) * bf[s];  // final-layer bias, once per atom
        m = mE;
    }
    // block reduction: 10 waves of 64
    float v = contrib;
    v += __shfl_down(v, 32);
    v += __shfl_down(v, 16);
    v += __shfl_down(v, 8);
    v += __shfl_down(v, 4);
    v += __shfl_down(v, 2);
    v += __shfl_down(v, 1);
    if ((t & 63) == 0) atomicAdd(&bsum, v);
    __syncthreads();
    if (t == 0) atomicAdd(out, bsum);
}

extern "C" void kernel_launch(void* const* d_in, const int* in_sizes, int n_in,
                              void* d_out, int out_size, void* d_ws, size_t ws_size,
                              hipStream_t stream) {
    const int*   species = (const int*)d_in[0];
    const float* coords  = (const float*)d_in[1];
    const float* EtaR    = (const float*)d_in[2];
    const float* ShfR    = (const float*)d_in[3];
    const float* W0      = (const float*)d_in[4];
    const float* b0      = (const float*)d_in[5];
    const float* W1      = (const float*)d_in[6];
    const float* b1      = (const float*)d_in[7];
    const float* W2      = (const float*)d_in[8];
    const float* b2      = (const float*)d_in[9];
    const float* Wf      = (const float*)d_in[10];
    const float* bf      = (const float*)d_in[11];
    float* out = (float*)d_out;
    char* ws = (char*)d_ws;

    int*    seg    = (int*)(ws + WS_SEG);
    float4* scoord = (float4*)(ws + WS_SCOORD);
    float*  aev    = (float*)(ws + WS_AEV);
    float*  h0buf  = (float*)(ws + WS_H0BUF);
    float*  h1buf  = (float*)(ws + WS_H1BUF);

    hipLaunchKernelGGL(sort_kernel, dim3(1), dim3(256), 0, stream,
                       species, coords, seg, scoord, out);
    hipLaunchKernelGGL(aev_kernel, dim3(N_ATOMS), dim3(128), 0, stream,
                       scoord, seg, ShfR, EtaR, aev);
    hipLaunchKernelGGL(mlp0_kernel, dim3(N_ATOMS / 8), dim3(1024), 0, stream,
                       W0, b0, aev, seg, h0buf);
    hipLaunchKernelGGL(mlp1_kernel, dim3(N_ATOMS / 8), dim3(768), 0, stream,
                       W1, b1, h0buf, seg, h1buf);
    hipLaunchKernelGGL(mlp2_kernel, dim3(N_ATOMS / 8), dim3(640), 0, stream,
                       W2, b2, Wf, bf, h1buf, seg, out);
}

// Round 3
// 153.069 us; speedup vs baseline: 1.4089x; 1.3432x over previous
//
#include <hip/hip_runtime.h>

#define N_ATOMS 2048
#define NSPEC 7
#define NR 16
#define NFEAT 112          // 7 species * 16 radial shifts; aev[112:1008] is zero padding
#define RCR_F 5.2f
#define H0 256
#define H1 192
#define H2 160
#define W0_PITCH 1008      // W0 rows are 1008 wide; only first 112 columns matter
#define TILE 8             // atoms per MLP block
#define NTILES (N_ATOMS / TILE)

// ---- workspace layout (byte offsets into d_ws; poisoned 0xAA each call, we init all) ----
#define WS_SEG     0         // int[8]   species segment starts (seg[7] = N)
#define WS_SCOORD  16384     // float4[2048] species-sorted coordinates
#define WS_AEV     65536     // float[2048*112] AEV per sorted atom
#define WS_H0BUF   1048576   // float[2048*256]
#define WS_H1BUF   3145728   // float[2048*192]

__device__ __forceinline__ float celu01(float x) {
    return x > 0.f ? x : 0.1f * (__expf(x * 10.f) - 1.f);
}

// ---------------- K0: counting sort by species + init ----------------
__global__ __launch_bounds__(256) void sort_kernel(const int* __restrict__ species,
                                                   const float* __restrict__ coords,
                                                   int* __restrict__ seg,
                                                   float4* __restrict__ scoord,
                                                   float* __restrict__ out) {
    __shared__ int cnt[NSPEC];
    __shared__ int cur[NSPEC];
    int t = threadIdx.x;
    if (t < NSPEC) cnt[t] = 0;
    __syncthreads();
    for (int a = t; a < N_ATOMS; a += 256) atomicAdd(&cnt[species[a]], 1);
    __syncthreads();
    if (t == 0) {
        int run = 0;
        for (int s = 0; s < NSPEC; s++) { seg[s] = run; cur[s] = run; run += cnt[s]; }
        seg[NSPEC] = run;
        out[0] = 0.0f;   // d_out is poisoned before every call
    }
    __syncthreads();
    for (int a = t; a < N_ATOMS; a += 256) {
        int sp = species[a];
        int pos = atomicAdd(&cur[sp], 1);
        scoord[pos] = make_float4(coords[3*a], coords[3*a+1], coords[3*a+2], 0.f);
    }
}

// ---------------- K1: radial AEV, one 128-thread block (2 waves) per sorted atom ----
__global__ __launch_bounds__(128) void aev_kernel(const float4* __restrict__ scoord,
                                                  const int* __restrict__ seg,
                                                  const float* __restrict__ ShfR,
                                                  const float* __restrict__ EtaR,
                                                  float* __restrict__ aev) {
    int p = blockIdx.x;
    int L = threadIdx.x;
    int s = L >> 4, c = L & 15;
    float4 ci = scoord[p];
    float eta = EtaR[0];
    float shf[NR];
#pragma unroll
    for (int r = 0; r < NR; r++) shf[r] = ShfR[r];   // uniform -> SGPRs
    float acc[NR];
#pragma unroll
    for (int r = 0; r < NR; r++) acc[r] = 0.f;

    int kbeg = 0, kend = 0;
    if (s < NSPEC) { kbeg = seg[s] + c; kend = seg[s + 1]; }
    const float rc2 = RCR_F * RCR_F;
    const float cosk = 3.14159265358979f / RCR_F;

    for (int k = kbeg; k < kend; k += 16) {
        float4 cj = scoord[k];
        float dx = ci.x - cj.x, dy = ci.y - cj.y, dz = ci.z - cj.z;
        float dsq = dx*dx + dy*dy + dz*dz;
        bool valid = (dsq > 0.f) && (dsq <= rc2);   // excludes self (j==i)
        float d = sqrtf(dsq);
        float fc = 0.5f * __cosf(d * cosk) + 0.5f;
        fc = valid ? fc : 0.f;
#pragma unroll
        for (int r = 0; r < NR; r++) {
            float u = d - shf[r];
            acc[r] = fmaf(__expf(-eta * u * u), fc, acc[r]);  // underflow -> 0, matches ref
        }
    }
#pragma unroll
    for (int r = 0; r < NR; r++) {
        float v = acc[r];
        v += __shfl_xor(v, 1);
        v += __shfl_xor(v, 2);
        v += __shfl_xor(v, 4);
        v += __shfl_xor(v, 8);
        acc[r] = v;
    }
    if (s < NSPEC && c == 0) {
        float* dst = aev + p * NFEAT + s * NR;
#pragma unroll
        for (int r = 0; r < NR; r += 4)
            *(float4*)(dst + r) = make_float4(acc[r], acc[r+1], acc[r+2], acc[r+3]);
    }
}

// ================= MLP layers =================
// Grid (NTILES, NSPEC): block handles TILE=8 atoms starting at seg[s]+tile*8,
// species = blockIdx.y (wave-uniform). All loops compile-time -> acc[] in
// registers (NOT scratch). Activations staged in LDS (contiguous slab,
// coalesced copy); compute-side LDS reads are 2/4-way broadcast (free).
// Thread t = o*KS + ks: output o, k-slice ks; shfl_xor reduce over ks.

// ---------------- K2a: layer0  aev[112] -> h0[256], 512 threads (KS=2) ------
__global__ __launch_bounds__(512) void mlp0_kernel(const float* __restrict__ W0,
                                                   const float* __restrict__ b0,
                                                   const float* __restrict__ aev,
                                                   const int* __restrict__ seg,
                                                   float* __restrict__ h0out) {
    __shared__ float4 hs[TILE * (NFEAT / 4)];   // 8 x 112 floats = 3.5 KB
    int s = blockIdx.y;
    int base = seg[s] + blockIdx.x * TILE;
    int segend = seg[s + 1];
    if (base >= segend) return;
    int n_act = min(TILE, segend - base);

    int t = threadIdx.x;
    {   // stage: contiguous slab aev[base*112 .. +8*112)
        const float4* src = (const float4*)(aev + (size_t)base * NFEAT);
        int nfl4 = min(TILE * (NFEAT / 4), (N_ATOMS - base) * (NFEAT / 4));
        for (int j = t; j < nfl4; j += 512) hs[j] = src[j];
    }
    __syncthreads();

    int o = t >> 1, ks = t & 1;
    const float* Wrow = W0 + (size_t)(s * H0 + o) * W0_PITCH + ks * 4;
    float bias = b0[s * H0 + o];
    float acc[TILE];
#pragma unroll
    for (int q = 0; q < TILE; q++) acc[q] = 0.f;

#pragma unroll 7
    for (int i = 0; i < NFEAT / 8; i++) {          // 14 iters, 8 floats per (i)
        float4 w = *(const float4*)(Wrow + i * 8);
#pragma unroll
        for (int q = 0; q < TILE; q++) {
            float4 a = hs[q * (NFEAT / 4) + i * 2 + ks];
            acc[q] += w.x*a.x + w.y*a.y + w.z*a.z + w.w*a.w;
        }
    }
#pragma unroll
    for (int q = 0; q < TILE; q++) {
        float v = acc[q];
        v += __shfl_xor(v, 1);
        if (ks == 0 && q < n_act)
            h0out[(size_t)(base + q) * H0 + o] = celu01(v + bias);
    }
}

// ---------------- K2b: layer1  h0[256] -> h1[192], 768 threads (KS=4) -------
__global__ __launch_bounds__(768) void mlp1_kernel(const float* __restrict__ W1,
                                                   const float* __restrict__ b1,
                                                   const float* __restrict__ h0,
                                                   const int* __restrict__ seg,
                                                   float* __restrict__ h1out) {
    __shared__ float4 hs[TILE * (H0 / 4)];      // 8 x 256 floats = 8 KB
    int s = blockIdx.y;
    int base = seg[s] + blockIdx.x * TILE;
    int segend = seg[s + 1];
    if (base >= segend) return;
    int n_act = min(TILE, segend - base);

    int t = threadIdx.x;
    {
        const float4* src = (const float4*)(h0 + (size_t)base * H0);
        int nfl4 = min(TILE * (H0 / 4), (N_ATOMS - base) * (H0 / 4));
        for (int j = t; j < nfl4; j += 768) hs[j] = src[j];
    }
    __syncthreads();

    int o = t >> 2, ks = t & 3;
    const float* Wrow = W1 + (size_t)(s * H1 + o) * H0 + ks * 4;
    float bias = b1[s * H1 + o];
    float acc[TILE];
#pragma unroll
    for (int q = 0; q < TILE; q++) acc[q] = 0.f;

#pragma unroll 4
    for (int i = 0; i < H0 / 16; i++) {            // 16 iters, 16 floats per (i)
        float4 w = *(const float4*)(Wrow + i * 16);
#pragma unroll
        for (int q = 0; q < TILE; q++) {
            float4 a = hs[q * (H0 / 4) + i * 4 + ks];
            acc[q] += w.x*a.x + w.y*a.y + w.z*a.z + w.w*a.w;
        }
    }
#pragma unroll
    for (int q = 0; q < TILE; q++) {
        float v = acc[q];
        v += __shfl_xor(v, 1);
        v += __shfl_xor(v, 2);
        if (ks == 0 && q < n_act)
            h1out[(size_t)(base + q) * H1 + o] = celu01(v + bias);
    }
}

// ---------------- K2c: layer2 + final dot + global sum, 640 threads (KS=4) --
__global__ __launch_bounds__(640) void mlp2_kernel(const float* __restrict__ W2,
                                                   const float* __restrict__ b2,
                                                   const float* __restrict__ Wf,
                                                   const float* __restrict__ bf,
                                                   const float* __restrict__ h1,
                                                   const int* __restrict__ seg,
                                                   float* __restrict__ out) {
    __shared__ float4 hs[TILE * (H1 / 4)];      // 8 x 192 floats = 6 KB
    __shared__ float bsum;
    int s = blockIdx.y;
    int base = seg[s] + blockIdx.x * TILE;
    int segend = seg[s + 1];
    if (base >= segend) return;
    int n_act = min(TILE, segend - base);

    int t = threadIdx.x;
    if (t == 0) bsum = 0.f;
    {
        const float4* src = (const float4*)(h1 + (size_t)base * H1);
        int nfl4 = min(TILE * (H1 / 4), (N_ATOMS - base) * (H1 / 4));
        for (int j = t; j < nfl4; j += 640) hs[j] = src[j];
    }
    __syncthreads();

    int o = t >> 2, ks = t & 3;
    const float* Wrow = W2 + (size_t)(s * H2 + o) * H1 + ks * 4;
    float bias = b2[s * H2 + o];
    float wf = Wf[s * H2 + o];
    float acc[TILE];
#pragma unroll
    for (int q = 0; q < TILE; q++) acc[q] = 0.f;

#pragma unroll 4
    for (int i = 0; i < H1 / 16; i++) {            // 12 iters
        float4 w = *(const float4*)(Wrow + i * 16);
#pragma unroll
        for (int q = 0; q < TILE; q++) {
            float4 a = hs[q * (H1 / 4) + i * 4 + ks];
            acc[q] += w.x*a.x + w.y*a.y + w.z*a.z + w.w*a.w;
        }
    }
    float contrib = 0.f;
#pragma unroll
    for (int q = 0; q < TILE; q++) {
        float v = acc[q];
        v += __shfl_xor(v, 1);
        v += __shfl_xor(v, 2);
        if (ks == 0 && q < n_act)
            contrib += wf * celu01(v + bias);
    }
    if (t == 0) contrib += (float)n_act * bf[s];   // final-layer bias, once per atom

    float v = contrib;
    v += __shfl_down(v, 32);
    v += __shfl_down(v, 16);
    v += __shfl_down(v, 8);
    v += __shfl_down(v, 4);
    v += __shfl_down(v, 2);
    v += __shfl_down(v, 1);
    if ((t & 63) == 0) atomicAdd(&bsum, v);
    __syncthreads();
    if (t == 0) atomicAdd(out, bsum);
}

extern "C" void kernel_launch(void* const* d_in, const int* in_sizes, int n_in,
                              void* d_out, int out_size, void* d_ws, size_t ws_size,
                              hipStream_t stream) {
    const int*   species = (const int*)d_in[0];
    const float* coords  = (const float*)d_in[1];
    const float* EtaR    = (const float*)d_in[2];
    const float* ShfR    = (const float*)d_in[3];
    const float* W0      = (const float*)d_in[4];
    const float* b0      = (const float*)d_in[5];
    const float* W1      = (const float*)d_in[6];
    const float* b1      = (const float*)d_in[7];
    const float* W2      = (const float*)d_in[8];
    const float* b2      = (const float*)d_in[9];
    const float* Wf      = (const float*)d_in[10];
    const float* bf      = (const float*)d_in[11];
    float* out = (float*)d_out;
    char* ws = (char*)d_ws;

    int*    seg    = (int*)(ws + WS_SEG);
    float4* scoord = (float4*)(ws + WS_SCOORD);
    float*  aev    = (float*)(ws + WS_AEV);
    float*  h0buf  = (float*)(ws + WS_H0BUF);
    float*  h1buf  = (float*)(ws + WS_H1BUF);

    hipLaunchKernelGGL(sort_kernel, dim3(1), dim3(256), 0, stream,
                       species, coords, seg, scoord, out);
    hipLaunchKernelGGL(aev_kernel, dim3(N_ATOMS), dim3(128), 0, stream,
                       scoord, seg, ShfR, EtaR, aev);
    hipLaunchKernelGGL(mlp0_kernel, dim3(NTILES, NSPEC), dim3(512), 0, stream,
                       W0, b0, aev, seg, h0buf);
    hipLaunchKernelGGL(mlp1_kernel, dim3(NTILES, NSPEC), dim3(768), 0, stream,
                       W1, b1, h0buf, seg, h1buf);
    hipLaunchKernelGGL(mlp2_kernel, dim3(NTILES, NSPEC), dim3(640), 0, stream,
                       W2, b2, Wf, bf, h1buf, seg, out);
}